// Round 9
// baseline (457.177 us; speedup 1.0000x reference)
//
#include <hip/hip_runtime.h>
#include <cstddef>

// Problem constants (static per reference)
#define B_ 2
#define Q_ 300
#define T_ 25
#define C_ 256
#define NH_ 8
#define NL_ 4
#define NP_ 4
#define HD_ 32
#define DFF_ 1024
#define LQ_ (Q_ * T_)           // 7500
#define NTOK_ (B_ * LQ_)        // 15000
#define S_ 21760                // sum of level sizes
#define BS_ (B_ * S_)           // 43520

typedef __bf16 bf16x8 __attribute__((ext_vector_type(8)));
typedef float floatx4 __attribute__((ext_vector_type(4)));
typedef unsigned short ushort_t;

// round-half-up bf16 pack: lo16 = bf16(x), hi16 = bf16(y). Folds to v_perm.
__device__ __forceinline__ unsigned pack_bf16(float x, float y) {
    unsigned ux = __float_as_uint(x) + 0x8000u;
    unsigned uy = __float_as_uint(y) + 0x8000u;
    return (ux >> 16) | (uy & 0xFFFF0000u);
}
__device__ __forceinline__ ushort_t f2bf_s(float x) {
    return (ushort_t)((__float_as_uint(x) + 0x8000u) >> 16);
}
__device__ __forceinline__ float bf2f(ushort_t u) {
    return __uint_as_float((unsigned)u << 16);
}

#define GBN 128
#define GBK 32
#define LDA_S 40   // LDS row stride in bf16 (pad 32 -> 40 to break bank stride)

// ---------------- generic bf16-MFMA GEMM (as R8): 1-deep prefetch, dual-W, split-K ----------
// AMODE: 0 = A fp32; 1 = A fp32 + A2; 2 = A bf16. OUT_BF16: bf16 C (no split-K).
template<int AMODE, int OUT_BF16, int GBMT>
__global__ __launch_bounds__(256) void gemm_t(
    const void* __restrict__ Av, const float* __restrict__ A2,
    const float* __restrict__ W, const float* __restrict__ W2, int N1,
    const float* __restrict__ bias, const float* __restrict__ bias2,
    void* __restrict__ Cv, long long partStride,
    int M, int N, int K, int kChunk, int ldc, int relu)
{
    constexpr int LA = GBMT / 32;
    constexpr int WM = GBMT / 2;
    constexpr int NI = WM / 16;

    __shared__ unsigned short Asl[GBMT * LDA_S];
    __shared__ unsigned short Bsl[GBN * LDA_S];

    const int m0 = blockIdx.x * GBMT;
    const int n0 = blockIdx.y * GBN;
    const int z  = blockIdx.z;
    const int kbeg = z * kChunk;
    const int kend = min(K, kbeg + kChunk);

    const int t  = threadIdx.x;
    const int wid  = t >> 6;
    const int lane = t & 63;
    const int wm = (wid >> 1) * WM;
    const int wn = (wid & 1) * 64;
    const int fm = lane & 15;
    const int fq = (lane >> 4) * 8;

    floatx4 acc[NI][4];
    #pragma unroll
    for (int i = 0; i < NI; ++i)
        #pragma unroll
        for (int j = 0; j < 4; ++j)
            acc[i][j] = (floatx4){0.f, 0.f, 0.f, 0.f};

    float4 pa[LA];
    uint2  pab[LA];
    float4 pw[4];
    const float* Af = (const float*)Av;
    const ushort_t* Ab = (const ushort_t*)Av;

    auto load_tiles = [&](int k0) {
        #pragma unroll
        for (int i = 0; i < LA; ++i) {
            int idx = t + 256 * i;
            int row = idx >> 3;
            int c4  = (idx & 7) * 4;
            int gm = m0 + row;
            if constexpr (AMODE == 2) {
                uint2 v = {0u, 0u};
                if (gm < M) v = *(const uint2*)(Ab + (size_t)gm * K + k0 + c4);
                pab[i] = v;
            } else {
                float4 v = make_float4(0.f, 0.f, 0.f, 0.f);
                if (gm < M) {
                    v = *(const float4*)(Af + (size_t)gm * K + k0 + c4);
                    if constexpr (AMODE == 1) {
                        float4 v2 = *(const float4*)(A2 + (size_t)gm * K + k0 + c4);
                        v.x += v2.x; v.y += v2.y; v.z += v2.z; v.w += v2.w;
                    }
                }
                pa[i] = v;
            }
        }
        #pragma unroll
        for (int i = 0; i < 4; ++i) {
            int idx = t + 256 * i;
            int row = idx >> 3;
            int c4  = (idx & 7) * 4;
            int gn = n0 + row;
            const float* wr;
            if (W2 && gn >= N1) wr = W2 + (size_t)(gn - N1) * K;
            else                wr = W + (size_t)gn * K;
            pw[i] = *(const float4*)(wr + k0 + c4);
        }
    };

    load_tiles(kbeg);
    for (int k0 = kbeg; k0 < kend; k0 += GBK) {
        #pragma unroll
        for (int i = 0; i < LA; ++i) {
            int idx = t + 256 * i;
            int row = idx >> 3;
            int c4  = (idx & 7) * 4;
            if constexpr (AMODE == 2) {
                *(uint2*)&Asl[row * LDA_S + c4] = pab[i];
            } else {
                uint2 p;
                p.x = pack_bf16(pa[i].x, pa[i].y);
                p.y = pack_bf16(pa[i].z, pa[i].w);
                *(uint2*)&Asl[row * LDA_S + c4] = p;
            }
        }
        #pragma unroll
        for (int i = 0; i < 4; ++i) {
            int idx = t + 256 * i;
            int row = idx >> 3;
            int c4  = (idx & 7) * 4;
            uint2 q;
            q.x = pack_bf16(pw[i].x, pw[i].y);
            q.y = pack_bf16(pw[i].z, pw[i].w);
            *(uint2*)&Bsl[row * LDA_S + c4] = q;
        }
        __syncthreads();

        if (k0 + GBK < kend) load_tiles(k0 + GBK);

        bf16x8 af[NI], bfr[4];
        #pragma unroll
        for (int i = 0; i < NI; ++i)
            af[i] = *(const bf16x8*)&Asl[(wm + i * 16 + fm) * LDA_S + fq];
        #pragma unroll
        for (int j = 0; j < 4; ++j)
            bfr[j] = *(const bf16x8*)&Bsl[(wn + j * 16 + fm) * LDA_S + fq];

        #pragma unroll
        for (int i = 0; i < NI; ++i)
            #pragma unroll
            for (int j = 0; j < 4; ++j)
                acc[i][j] = __builtin_amdgcn_mfma_f32_16x16x32_bf16(af[i], bfr[j], acc[i][j], 0, 0, 0);
        __syncthreads();
    }

    float* Cf = (float*)Cv + (long long)z * partStride;
    ushort_t* Cb = (ushort_t*)Cv;
    const int cr = (lane >> 4) * 4;
    const int cc = lane & 15;
    #pragma unroll
    for (int j = 0; j < 4; ++j) {
        int gn = n0 + wn + j * 16 + cc;
        float bia = 0.f;
        if (z == 0) bia = (bias2 && gn >= N1) ? bias2[gn - N1] : bias[gn];
        #pragma unroll
        for (int i = 0; i < NI; ++i) {
            #pragma unroll
            for (int r = 0; r < 4; ++r) {
                int gm = m0 + wm + i * 16 + cr + r;
                if (gm < M) {
                    float v = acc[i][j][r] + bia;
                    if (relu) v = fmaxf(v, 0.f);
                    if constexpr (OUT_BF16) Cb[(size_t)gm * ldc + gn] = f2bf_s(v);
                    else                    Cf[(size_t)gm * ldc + gn] = v;
                }
            }
        }
    }
}

// ---------------- fused 3-segment projection GEMM (QK | V | value-proj) -----------------
// One dispatch, 2770 blocks of 256. K=256, M-tile 64, N-tile 128 everywhere.
//  seg0 [0,940):    qk = (tgt+pos) @ ipw[0:512]^T   -> qkv bf16 cols 0..511 (ldc 768)
//  seg1 [940,1410): v  = tgt @ ipw[512:768]^T       -> qkv bf16 cols 512..767
//  seg2 [1410,2770): value = src @ vpw^T            -> valt bf16 TRANSPOSED [B][NH][S][HD]
__global__ __launch_bounds__(256) void gemm3(
    const float* __restrict__ tgt, const float* __restrict__ pos,
    const float* __restrict__ src,
    const float* __restrict__ ipw, const float* __restrict__ ipb,
    const float* __restrict__ vpw, const float* __restrict__ vpb,
    ushort_t* __restrict__ qkv, ushort_t* __restrict__ valt)
{
    __shared__ unsigned short Asl[64 * LDA_S];
    __shared__ unsigned short Bsl[GBN * LDA_S];

    int g = blockIdx.x;
    const float *A, *A2, *W, *bias;
    int m0, n0, M, vt;
    ushort_t* C;
    if (g < 940)       { A = tgt; A2 = pos;     W = ipw;             bias = ipb;
                         m0 = (g >> 2) * 64; n0 = (g & 3) * 128; M = NTOK_; vt = 0; C = qkv; }
    else if (g < 1410) { g -= 940; A = tgt; A2 = nullptr; W = ipw + 512 * 256; bias = ipb + 512;
                         m0 = (g >> 1) * 64; n0 = (g & 1) * 128; M = NTOK_; vt = 0; C = qkv + 512; }
    else               { g -= 1410; A = src; A2 = nullptr; W = vpw;  bias = vpb;
                         m0 = (g >> 1) * 64; n0 = (g & 1) * 128; M = BS_; vt = 1; C = valt; }
    const int K = 256;

    const int t  = threadIdx.x;
    const int wid  = t >> 6;
    const int lane = t & 63;
    const int wm = (wid >> 1) * 32;
    const int wn = (wid & 1) * 64;
    const int fm = lane & 15;
    const int fq = (lane >> 4) * 8;

    floatx4 acc[2][4];
    #pragma unroll
    for (int i = 0; i < 2; ++i)
        #pragma unroll
        for (int j = 0; j < 4; ++j)
            acc[i][j] = (floatx4){0.f, 0.f, 0.f, 0.f};

    float4 pa[2], pw[4];
    auto load_tiles = [&](int k0) {
        #pragma unroll
        for (int i = 0; i < 2; ++i) {
            int idx = t + 256 * i;
            int row = idx >> 3;
            int c4  = (idx & 7) * 4;
            int gm = m0 + row;
            float4 v = make_float4(0.f, 0.f, 0.f, 0.f);
            if (gm < M) {
                v = *(const float4*)(A + (size_t)gm * K + k0 + c4);
                if (A2) {
                    float4 v2 = *(const float4*)(A2 + (size_t)gm * K + k0 + c4);
                    v.x += v2.x; v.y += v2.y; v.z += v2.z; v.w += v2.w;
                }
            }
            pa[i] = v;
        }
        #pragma unroll
        for (int i = 0; i < 4; ++i) {
            int idx = t + 256 * i;
            int row = idx >> 3;
            int c4  = (idx & 7) * 4;
            pw[i] = *(const float4*)(W + (size_t)(n0 + row) * K + k0 + c4);
        }
    };

    load_tiles(0);
    for (int k0 = 0; k0 < K; k0 += GBK) {
        #pragma unroll
        for (int i = 0; i < 2; ++i) {
            int idx = t + 256 * i;
            int row = idx >> 3;
            int c4  = (idx & 7) * 4;
            uint2 p;
            p.x = pack_bf16(pa[i].x, pa[i].y);
            p.y = pack_bf16(pa[i].z, pa[i].w);
            *(uint2*)&Asl[row * LDA_S + c4] = p;
        }
        #pragma unroll
        for (int i = 0; i < 4; ++i) {
            int idx = t + 256 * i;
            int row = idx >> 3;
            int c4  = (idx & 7) * 4;
            uint2 q;
            q.x = pack_bf16(pw[i].x, pw[i].y);
            q.y = pack_bf16(pw[i].z, pw[i].w);
            *(uint2*)&Bsl[row * LDA_S + c4] = q;
        }
        __syncthreads();

        if (k0 + GBK < K) load_tiles(k0 + GBK);

        bf16x8 af[2], bfr[4];
        #pragma unroll
        for (int i = 0; i < 2; ++i)
            af[i] = *(const bf16x8*)&Asl[(wm + i * 16 + fm) * LDA_S + fq];
        #pragma unroll
        for (int j = 0; j < 4; ++j)
            bfr[j] = *(const bf16x8*)&Bsl[(wn + j * 16 + fm) * LDA_S + fq];

        #pragma unroll
        for (int i = 0; i < 2; ++i)
            #pragma unroll
            for (int j = 0; j < 4; ++j)
                acc[i][j] = __builtin_amdgcn_mfma_f32_16x16x32_bf16(af[i], bfr[j], acc[i][j], 0, 0, 0);
        __syncthreads();
    }

    const int cr = (lane >> 4) * 4;
    const int cc = lane & 15;
    #pragma unroll
    for (int j = 0; j < 4; ++j) {
        int gn = n0 + wn + j * 16 + cc;
        float bia = bias[gn];
        #pragma unroll
        for (int i = 0; i < 2; ++i) {
            #pragma unroll
            for (int r = 0; r < 4; ++r) {
                int gm = m0 + wm + i * 16 + cr + r;
                if (gm < M) {
                    ushort_t o = f2bf_s(acc[i][j][r] + bia);
                    if (vt) {
                        int bb = gm >= S_;
                        int s  = gm - bb * S_;
                        C[(((size_t)(bb * 8 + (gn >> 5))) * S_ + s) * 32 + (gn & 31)] = o;
                    } else {
                        C[(size_t)gm * 768 + gn] = o;
                    }
                }
            }
        }
    }
}

// ---------------- self-attention over T=25, one wave per (seq, head); bf16 in/out ----------------
__global__ __launch_bounds__(64) void attn_kernel(
    const ushort_t* __restrict__ qkv,   // [NTOK, 768] bf16: q|k|v per token
    ushort_t* __restrict__ o)           // [NTOK, 256] bf16
{
    int sh = blockIdx.x;
    int s = sh >> 3, h = sh & 7;
    __shared__ float qs[T_][HD_], ks[T_][HD_], vs[T_][HD_];
    int t = threadIdx.x;

    for (int idx = t; idx < T_ * HD_; idx += 64) {
        int i = idx >> 5, d = idx & 31;
        size_t base = ((size_t)(s * T_ + i)) * 768 + h * HD_ + d;
        qs[i][d] = bf2f(qkv[base]);
        ks[i][d] = bf2f(qkv[base + 256]);
        vs[i][d] = bf2f(qkv[base + 512]);
    }
    __syncthreads();

    if (t < T_) {
        float sc[T_];
        float mx = -1e30f;
        #pragma unroll
        for (int j = 0; j < T_; ++j) {
            float dot = 0.f;
            #pragma unroll
            for (int d = 0; d < HD_; ++d) dot += qs[t][d] * ks[j][d];
            sc[j] = dot * 0.17677669529663687f;
            mx = fmaxf(mx, sc[j]);
        }
        float sum = 0.f;
        #pragma unroll
        for (int j = 0; j < T_; ++j) { sc[j] = __expf(sc[j] - mx); sum += sc[j]; }
        float inv = 1.f / sum;
        float out[HD_];
        #pragma unroll
        for (int d = 0; d < HD_; ++d) out[d] = 0.f;
        for (int j = 0; j < T_; ++j) {
            float p = sc[j] * inv;
            #pragma unroll
            for (int d = 0; d < HD_; ++d) out[d] += p * vs[j][d];
        }
        size_t ob = ((size_t)(s * T_ + t)) * C_ + h * HD_;
        #pragma unroll
        for (int d = 0; d < HD_; ++d) o[ob + d] = f2bf_s(out[d]);
    }
}

// ---------------- wave-per-token residual + LayerNorm (float4, no LDS) ----------------
__global__ __launch_bounds__(256) void ln4_kernel(
    const float* __restrict__ x, const float* __restrict__ r,
    int nparts, long long rstride,
    const float* __restrict__ g, const float* __restrict__ b,
    float* __restrict__ out, const float* __restrict__ pos,
    float* __restrict__ qout)
{
    const int wave = threadIdx.x >> 6;
    const int lane = threadIdx.x & 63;
    const int tok = blockIdx.x * 4 + wave;
    const size_t base = (size_t)tok * C_ + lane * 4;

    float4 v = *(const float4*)(x + base);
    for (int p = 0; p < nparts; ++p) {
        float4 rv = *(const float4*)(r + base + (long long)p * rstride);
        v.x += rv.x; v.y += rv.y; v.z += rv.z; v.w += rv.w;
    }
    float s  = v.x + v.y + v.z + v.w;
    float ss = v.x * v.x + v.y * v.y + v.z * v.z + v.w * v.w;
    #pragma unroll
    for (int m = 32; m; m >>= 1) {
        s  += __shfl_xor(s, m);
        ss += __shfl_xor(ss, m);
    }
    float mean = s * (1.f / 256.f);
    float var  = ss * (1.f / 256.f) - mean * mean;
    float rstd = rsqrtf(var + 1e-5f);

    float4 gv = *(const float4*)(g + lane * 4);
    float4 bv = *(const float4*)(b + lane * 4);
    float4 y;
    y.x = (v.x - mean) * rstd * gv.x + bv.x;
    y.y = (v.y - mean) * rstd * gv.y + bv.y;
    y.z = (v.z - mean) * rstd * gv.z + bv.z;
    y.w = (v.w - mean) * rstd * gv.w + bv.w;
    *(float4*)(out + base) = y;
    if (qout) {
        float4 pv = *(const float4*)(pos + base);
        float4 q;
        q.x = y.x + pv.x; q.y = y.y + pv.y; q.z = y.z + pv.z; q.w = y.w + pv.w;
        *(float4*)(qout + base) = q;
    }
}

// ---------------- deformable sampling: 2 tokens/wave, 4 lanes/head; value [B][NH][S][HD] bf16 ----
__global__ __launch_bounds__(256) void deform_kernel(
    const ushort_t* __restrict__ value,   // [B][NH][S][HD] bf16 (transposed)
    const float* __restrict__ d12,        // [NTOK, 384] = offsets | aw logits
    const float* __restrict__ refpts,     // [B, LQ, NL, 2]
    ushort_t* __restrict__ out)           // [NTOK, 256] bf16, laid out (tok, h, d)
{
    const int lane = threadIdx.x & 63;
    const int wave = threadIdx.x >> 6;
    const int half = lane >> 5;
    const int tok = blockIdx.x * 8 + wave * 2 + half;
    const int h  = (lane >> 2) & 7;
    const int d8 = (lane & 3) * 8;
    const int b = tok / LQ_;

    const float* awp = d12 + (size_t)tok * 384 + 256 + h * 16;
    float logit[16];
    float mx = -1e30f;
    #pragma unroll
    for (int i = 0; i < 16; ++i) { logit[i] = awp[i]; mx = fmaxf(mx, logit[i]); }
    float sum = 0.f;
    #pragma unroll
    for (int i = 0; i < 16; ++i) { logit[i] = __expf(logit[i] - mx); sum += logit[i]; }
    float inv = 1.f / sum;

    const float* offp = d12 + (size_t)tok * 384 + h * 32;
    const float* refp = refpts + (size_t)tok * (NL_ * 2);

    const int HW[4]     = {128, 64, 32, 16};
    const int starts[4] = {0, 16384, 20480, 21504};

    float accv[8];
    #pragma unroll
    for (int i = 0; i < 8; ++i) accv[i] = 0.f;

    #pragma unroll
    for (int l = 0; l < 4; ++l) {
        const int Hl = HW[l], Wl = HW[l];
        float rx = refp[l * 2 + 0], ry = refp[l * 2 + 1];
        const ushort_t* vbase = value + (((size_t)(b * 8 + h)) * S_ + starts[l]) * HD_ + d8;
        #pragma unroll
        for (int p = 0; p < 4; ++p) {
            float ox = offp[(l * 4 + p) * 2 + 0];
            float oy = offp[(l * 4 + p) * 2 + 1];
            float xl = rx * (float)Wl + ox - 0.5f;
            float yl = ry * (float)Hl + oy - 0.5f;
            float x0f = floorf(xl), y0f = floorf(yl);
            int x0 = (int)x0f, y0 = (int)y0f;
            float wx1 = xl - x0f, wy1 = yl - y0f;
            float wx0 = 1.f - wx1, wy0 = 1.f - wy1;
            float aww = logit[l * 4 + p] * inv;

            #pragma unroll
            for (int c = 0; c < 4; ++c) {
                int dx = c & 1, dy = c >> 1;
                int xi = x0 + dx, yi = y0 + dy;
                float w = (dx ? wx1 : wx0) * (dy ? wy1 : wy0);
                bool valid = (xi >= 0) & (xi < Wl) & (yi >= 0) & (yi < Hl);
                int xc = min(max(xi, 0), Wl - 1);
                int yc = min(max(yi, 0), Hl - 1);
                float wc = (valid ? w : 0.f) * aww;
                uint4 raw = *(const uint4*)(vbase + (size_t)(yc * Wl + xc) * HD_);
                accv[0] += __uint_as_float((raw.x & 0xFFFFu) << 16) * wc;
                accv[1] += __uint_as_float(raw.x & 0xFFFF0000u) * wc;
                accv[2] += __uint_as_float((raw.y & 0xFFFFu) << 16) * wc;
                accv[3] += __uint_as_float(raw.y & 0xFFFF0000u) * wc;
                accv[4] += __uint_as_float((raw.z & 0xFFFFu) << 16) * wc;
                accv[5] += __uint_as_float(raw.z & 0xFFFF0000u) * wc;
                accv[6] += __uint_as_float((raw.w & 0xFFFFu) << 16) * wc;
                accv[7] += __uint_as_float(raw.w & 0xFFFF0000u) * wc;
            }
        }
    }
    uint4 po;
    po.x = pack_bf16(accv[0], accv[1]);
    po.y = pack_bf16(accv[2], accv[3]);
    po.z = pack_bf16(accv[4], accv[5]);
    po.w = pack_bf16(accv[6], accv[7]);
    *(uint4*)(out + (size_t)tok * C_ + h * HD_ + d8) = po;
}

// ---------------- host launch ----------------
extern "C" void kernel_launch(void* const* d_in, const int* in_sizes, int n_in,
                              void* d_out, int out_size, void* d_ws, size_t ws_size,
                              hipStream_t stream) {
    const float* tgt_text = (const float*)d_in[0];
    const float* pos      = (const float*)d_in[1];
    const float* refpts   = (const float*)d_in[2];
    const float* src      = (const float*)d_in[3];
    const float* in_proj_w  = (const float*)d_in[6];
    const float* in_proj_b  = (const float*)d_in[7];
    const float* out_proj_w = (const float*)d_in[8];
    const float* out_proj_b = (const float*)d_in[9];
    const float* ln1_g = (const float*)d_in[10];
    const float* ln1_b = (const float*)d_in[11];
    const float* samp_off_w = (const float*)d_in[12];
    const float* samp_off_b = (const float*)d_in[13];
    const float* aw_w = (const float*)d_in[14];
    const float* aw_b = (const float*)d_in[15];
    const float* vp_w = (const float*)d_in[16];
    const float* vp_b = (const float*)d_in[17];
    const float* op_w = (const float*)d_in[18];
    const float* op_b = (const float*)d_in[19];
    const float* ln2_g = (const float*)d_in[20];
    const float* ln2_b = (const float*)d_in[21];
    const float* ffn1_w = (const float*)d_in[22];
    const float* ffn1_b = (const float*)d_in[23];
    const float* ffn2_w = (const float*)d_in[24];
    const float* ffn2_b = (const float*)d_in[25];
    const float* ln3_g = (const float*)d_in[26];
    const float* ln3_b = (const float*)d_in[27];

    const long long NC = (long long)NTOK_ * C_;    // 3,840,000 floats
    float* ws = (float*)d_ws;
    float* A    = ws;                               // [NTOK,C] fp32  tgt (post-LN1/LN2)
    float* Bq   = ws + NC;                          // [NTOK,C] fp32  query
    float* Creg = ws + 2 * NC;                      // 15.36M floats: qkv+valt -> ffn hidden
    float* D12  = Creg + (long long)NTOK_ * DFF_;   // [NTOK,384] fp32 offsets|aw
    float* E    = D12 + (long long)NTOK_ * 384;     // [NTOK,C]: bf16 attn/deform out; fp32 FFN2 partial0
    float* F    = E + NC;                           // [NTOK,C] fp32 proj results / FFN2 partial1

    ushort_t* qkv  = (ushort_t*)Creg;                       // [NTOK,768] bf16
    ushort_t* valt = (ushort_t*)Creg + (size_t)NTOK_ * 768; // [B][NH][S][HD] bf16

    const int MB64  = (NTOK_ + 63) / 64;    // 235
    const int MB128 = (NTOK_ + 127) / 128;  // 118

    // 1. fused: QK proj (tgt+pos), V proj (tgt), value proj (src, transposed store)
    gemm3<<<2770, 256, 0, stream>>>(tgt_text, pos, src, in_proj_w, in_proj_b,
                                    vp_w, vp_b, qkv, valt);
    // 2. self-attention (bf16 -> bf16)
    attn_kernel<<<B_ * Q_ * NH_, 64, 0, stream>>>(qkv, (ushort_t*)E);
    // 3. out projection (A bf16), 64-tile -> F fp32
    gemm_t<2, 0, 64><<<dim3(MB64, 2, 1), 256, 0, stream>>>(E, nullptr, out_proj_w, nullptr, 0,
        out_proj_b, nullptr, F, 0, NTOK_, 256, 256, 256, 256, 0);
    // 4. LN1 (+ residual), and query = tgt + pos
    ln4_kernel<<<NTOK_ / 4, 256, 0, stream>>>(tgt_text, F, 1, 0,
                                              ln1_g, ln1_b, A, pos, Bq);
    // 5. sampling offsets + aw logits, merged (N=384, dual weights) -> fp32 D12
    gemm_t<0, 0, 64><<<dim3(MB64, 3, 1), 256, 0, stream>>>(Bq, nullptr, samp_off_w, aw_w, 256,
        samp_off_b, aw_b, D12, 0, NTOK_, 384, 256, 256, 384, 0);
    // 6. deformable sampling (transposed bf16 value, bf16 out); 2 tokens per wave
    deform_kernel<<<NTOK_ / 8, 256, 0, stream>>>(valt, D12, refpts, (ushort_t*)E);
    // 7. output projection of cross-attn (A bf16), 64-tile -> F fp32
    gemm_t<2, 0, 64><<<dim3(MB64, 2, 1), 256, 0, stream>>>(E, nullptr, op_w, nullptr, 0,
        op_b, nullptr, F, 0, NTOK_, 256, 256, 256, 256, 0);
    // 8. LN2 (+ residual), in place on A
    ln4_kernel<<<NTOK_ / 4, 256, 0, stream>>>(A, F, 1, 0,
                                              ln2_g, ln2_b, A, nullptr, nullptr);
    // 9. FFN1 + ReLU -> bf16 hidden [NTOK,1024]; 128-tile (944 blocks)
    gemm_t<0, 1, 128><<<dim3(MB128, 8, 1), 256, 0, stream>>>(A, nullptr, ffn1_w, nullptr, 0,
        ffn1_b, nullptr, Creg, 0, NTOK_, DFF_, 256, 256, DFF_, 1);
    // 10. FFN2 (A bf16), 64-tile + split-K x2: partial0=E, partial1=F (=E+NC)
    gemm_t<2, 0, 64><<<dim3(MB64, 2, 2), 256, 0, stream>>>(Creg, nullptr, ffn2_w, nullptr, 0,
        ffn2_b, nullptr, E, NC, NTOK_, 256, 1024, 512, 256, 0);
    // 11. LN3 (+ residual over 2 partials) -> d_out
    ln4_kernel<<<NTOK_ / 4, 256, 0, stream>>>(A, E, 2, NC,
                                              ln3_g, ln3_b, (float*)d_out, nullptr, nullptr);
}

// Round 10
// 421.862 us; speedup vs baseline: 1.0837x; 1.0837x over previous
//
#include <hip/hip_runtime.h>
#include <cstddef>

// Problem constants (static per reference)
#define B_ 2
#define Q_ 300
#define T_ 25
#define C_ 256
#define NH_ 8
#define NL_ 4
#define NP_ 4
#define HD_ 32
#define DFF_ 1024
#define LQ_ (Q_ * T_)           // 7500
#define NTOK_ (B_ * LQ_)        // 15000
#define S_ 21760                // sum of level sizes
#define BS_ (B_ * S_)           // 43520

typedef __bf16 bf16x8 __attribute__((ext_vector_type(8)));
typedef float floatx4 __attribute__((ext_vector_type(4)));
typedef unsigned short ushort_t;

// round-half-up bf16 pack: lo16 = bf16(x), hi16 = bf16(y). Folds to v_perm.
__device__ __forceinline__ unsigned pack_bf16(float x, float y) {
    unsigned ux = __float_as_uint(x) + 0x8000u;
    unsigned uy = __float_as_uint(y) + 0x8000u;
    return (ux >> 16) | (uy & 0xFFFF0000u);
}
__device__ __forceinline__ ushort_t f2bf_s(float x) {
    return (ushort_t)((__float_as_uint(x) + 0x8000u) >> 16);
}
__device__ __forceinline__ float bf2f(ushort_t u) {
    return __uint_as_float((unsigned)u << 16);
}

// bf16 weight arena element offsets (all static shapes)
#define WOFF_IP   0         // in_proj   768x256
#define WOFF_OUT  196608    // out_proj  256x256
#define WOFF_VP   262144    // value_proj 256x256
#define WOFF_SO   327680    // samp_off  256x256  (contiguous with aw -> 384x256)
#define WOFF_AW   393216    // aw        128x256
#define WOFF_OP   425984    // op        256x256
#define WOFF_F1   491520    // ffn1      1024x256
#define WOFF_F2   753664    // ffn2      256x1024
#define WTOTAL    1015808

// ---------------- one-shot fp32 -> bf16 weight conversion (8 elems/thread) ----------------
__global__ __launch_bounds__(256) void convw_kernel(
    const float* __restrict__ ipw, const float* __restrict__ outw,
    const float* __restrict__ vpw, const float* __restrict__ sampw,
    const float* __restrict__ aww, const float* __restrict__ opw,
    const float* __restrict__ f1w, const float* __restrict__ f2w,
    ushort_t* __restrict__ dst)
{
    long long g = ((long long)blockIdx.x * 256 + threadIdx.x) * 8;
    if (g >= WTOTAL) return;
    const float* src; long long off;
    if      (g < WOFF_OUT) { src = ipw;   off = WOFF_IP; }
    else if (g < WOFF_VP)  { src = outw;  off = WOFF_OUT; }
    else if (g < WOFF_SO)  { src = vpw;   off = WOFF_VP; }
    else if (g < WOFF_AW)  { src = sampw; off = WOFF_SO; }
    else if (g < WOFF_OP)  { src = aww;   off = WOFF_AW; }
    else if (g < WOFF_F1)  { src = opw;   off = WOFF_OP; }
    else if (g < WOFF_F2)  { src = f1w;   off = WOFF_F1; }
    else                   { src = f2w;   off = WOFF_F2; }
    const float4* s4 = (const float4*)(src + (g - off));
    float4 a = s4[0], b = s4[1];
    uint4 o;
    o.x = pack_bf16(a.x, a.y); o.y = pack_bf16(a.z, a.w);
    o.z = pack_bf16(b.x, b.y); o.w = pack_bf16(b.z, b.w);
    *(uint4*)(dst + g) = o;
}

#define GBN 128
#define GBK 32
#define LDA_S 40   // LDS row stride in bf16 (pad 32 -> 40 to break bank stride)

// ---------------- bf16-MFMA GEMM; W pre-converted bf16; 1-deep prefetch; split-K ----------
// AMODE: 0 = A fp32; 1 = A fp32 + A2 fp32; 2 = A bf16.
// OUTMODE: 0 = fp32 C (split-K capable); 1 = bf16 C; 2 = bf16 C transposed value
//          layout [B][NH][S][HD] (M interpreted as b*S+s, N as h*32+d).
// bias2/N1: rows >= N1 take bias2 (weights already contiguous).
template<int AMODE, int OUTMODE, int GBMT>
__global__ __launch_bounds__(256) void gemm_w(
    const void* __restrict__ Av, const float* __restrict__ A2,
    const ushort_t* __restrict__ W,
    const float* __restrict__ bias, const float* __restrict__ bias2, int N1,
    void* __restrict__ Cv, long long partStride,
    int M, int N, int K, int kChunk, int ldc, int relu)
{
    constexpr int LA = GBMT / 32;
    constexpr int WM = GBMT / 2;
    constexpr int NI = WM / 16;

    __shared__ unsigned short Asl[GBMT * LDA_S];
    __shared__ unsigned short Bsl[GBN * LDA_S];

    const int m0 = blockIdx.x * GBMT;
    const int n0 = blockIdx.y * GBN;
    const int z  = blockIdx.z;
    const int kbeg = z * kChunk;
    const int kend = min(K, kbeg + kChunk);

    const int t  = threadIdx.x;
    const int wid  = t >> 6;
    const int lane = t & 63;
    const int wm = (wid >> 1) * WM;
    const int wn = (wid & 1) * 64;
    const int fm = lane & 15;
    const int fq = (lane >> 4) * 8;

    floatx4 acc[NI][4];
    #pragma unroll
    for (int i = 0; i < NI; ++i)
        #pragma unroll
        for (int j = 0; j < 4; ++j)
            acc[i][j] = (floatx4){0.f, 0.f, 0.f, 0.f};

    float4 pa[LA];
    uint2  pab[LA];
    uint2  pwb[4];
    const float* Af = (const float*)Av;
    const ushort_t* Ab = (const ushort_t*)Av;

    auto load_tiles = [&](int k0) {
        #pragma unroll
        for (int i = 0; i < LA; ++i) {
            int idx = t + 256 * i;
            int row = idx >> 3;
            int c4  = (idx & 7) * 4;
            int gm = m0 + row;
            if constexpr (AMODE == 2) {
                uint2 v = {0u, 0u};
                if (gm < M) v = *(const uint2*)(Ab + (size_t)gm * K + k0 + c4);
                pab[i] = v;
            } else {
                float4 v = make_float4(0.f, 0.f, 0.f, 0.f);
                if (gm < M) {
                    v = *(const float4*)(Af + (size_t)gm * K + k0 + c4);
                    if constexpr (AMODE == 1) {
                        float4 v2 = *(const float4*)(A2 + (size_t)gm * K + k0 + c4);
                        v.x += v2.x; v.y += v2.y; v.z += v2.z; v.w += v2.w;
                    }
                }
                pa[i] = v;
            }
        }
        #pragma unroll
        for (int i = 0; i < 4; ++i) {
            int idx = t + 256 * i;
            int row = idx >> 3;
            int c4  = (idx & 7) * 4;
            pwb[i] = *(const uint2*)(W + (size_t)(n0 + row) * K + k0 + c4);
        }
    };

    load_tiles(kbeg);
    for (int k0 = kbeg; k0 < kend; k0 += GBK) {
        #pragma unroll
        for (int i = 0; i < LA; ++i) {
            int idx = t + 256 * i;
            int row = idx >> 3;
            int c4  = (idx & 7) * 4;
            if constexpr (AMODE == 2) {
                *(uint2*)&Asl[row * LDA_S + c4] = pab[i];
            } else {
                uint2 p;
                p.x = pack_bf16(pa[i].x, pa[i].y);
                p.y = pack_bf16(pa[i].z, pa[i].w);
                *(uint2*)&Asl[row * LDA_S + c4] = p;
            }
        }
        #pragma unroll
        for (int i = 0; i < 4; ++i) {
            int idx = t + 256 * i;
            int row = idx >> 3;
            int c4  = (idx & 7) * 4;
            *(uint2*)&Bsl[row * LDA_S + c4] = pwb[i];
        }
        __syncthreads();

        if (k0 + GBK < kend) load_tiles(k0 + GBK);

        bf16x8 af[NI], bfr[4];
        #pragma unroll
        for (int i = 0; i < NI; ++i)
            af[i] = *(const bf16x8*)&Asl[(wm + i * 16 + fm) * LDA_S + fq];
        #pragma unroll
        for (int j = 0; j < 4; ++j)
            bfr[j] = *(const bf16x8*)&Bsl[(wn + j * 16 + fm) * LDA_S + fq];

        #pragma unroll
        for (int i = 0; i < NI; ++i)
            #pragma unroll
            for (int j = 0; j < 4; ++j)
                acc[i][j] = __builtin_amdgcn_mfma_f32_16x16x32_bf16(af[i], bfr[j], acc[i][j], 0, 0, 0);
        __syncthreads();
    }

    // epilogue: C/D layout col=lane&15, row=(lane>>4)*4+reg
    float* Cf = (float*)Cv + (long long)z * partStride;
    ushort_t* Cb = (ushort_t*)Cv;
    const int cr = (lane >> 4) * 4;
    const int cc = lane & 15;
    #pragma unroll
    for (int j = 0; j < 4; ++j) {
        int gn = n0 + wn + j * 16 + cc;
        float bia = 0.f;
        if (z == 0) bia = (bias2 && gn >= N1) ? bias2[gn - N1] : bias[gn];
        #pragma unroll
        for (int i = 0; i < NI; ++i) {
            #pragma unroll
            for (int r = 0; r < 4; ++r) {
                int gm = m0 + wm + i * 16 + cr + r;
                if (gm < M) {
                    float v = acc[i][j][r] + bia;
                    if (relu) v = fmaxf(v, 0.f);
                    if constexpr (OUTMODE == 2) {
                        int bb = gm >= S_;
                        int s  = gm - bb * S_;
                        Cb[(((size_t)(bb * 8 + (gn >> 5))) * S_ + s) * 32 + (gn & 31)] = f2bf_s(v);
                    } else if constexpr (OUTMODE == 1) {
                        Cb[(size_t)gm * ldc + gn] = f2bf_s(v);
                    } else {
                        Cf[(size_t)gm * ldc + gn] = v;
                    }
                }
            }
        }
    }
}

// ---------------- self-attention over T=25, one wave per (seq, head); bf16 in/out ----------------
__global__ __launch_bounds__(64) void attn_kernel(
    const ushort_t* __restrict__ qkv,   // [NTOK, 768] bf16: q|k|v per token
    ushort_t* __restrict__ o)           // [NTOK, 256] bf16
{
    int sh = blockIdx.x;
    int s = sh >> 3, h = sh & 7;
    __shared__ float qs[T_][HD_], ks[T_][HD_], vs[T_][HD_];
    int t = threadIdx.x;

    for (int idx = t; idx < T_ * HD_; idx += 64) {
        int i = idx >> 5, d = idx & 31;
        size_t base = ((size_t)(s * T_ + i)) * 768 + h * HD_ + d;
        qs[i][d] = bf2f(qkv[base]);
        ks[i][d] = bf2f(qkv[base + 256]);
        vs[i][d] = bf2f(qkv[base + 512]);
    }
    __syncthreads();

    if (t < T_) {
        float sc[T_];
        float mx = -1e30f;
        #pragma unroll
        for (int j = 0; j < T_; ++j) {
            float dot = 0.f;
            #pragma unroll
            for (int d = 0; d < HD_; ++d) dot += qs[t][d] * ks[j][d];
            sc[j] = dot * 0.17677669529663687f;
            mx = fmaxf(mx, sc[j]);
        }
        float sum = 0.f;
        #pragma unroll
        for (int j = 0; j < T_; ++j) { sc[j] = __expf(sc[j] - mx); sum += sc[j]; }
        float inv = 1.f / sum;
        float out[HD_];
        #pragma unroll
        for (int d = 0; d < HD_; ++d) out[d] = 0.f;
        for (int j = 0; j < T_; ++j) {
            float p = sc[j] * inv;
            #pragma unroll
            for (int d = 0; d < HD_; ++d) out[d] += p * vs[j][d];
        }
        size_t ob = ((size_t)(s * T_ + t)) * C_ + h * HD_;
        #pragma unroll
        for (int d = 0; d < HD_; ++d) o[ob + d] = f2bf_s(out[d]);
    }
}

// ---------------- wave-per-token residual + LayerNorm (float4, no LDS) ----------------
__global__ __launch_bounds__(256) void ln4_kernel(
    const float* __restrict__ x, const float* __restrict__ r,
    int nparts, long long rstride,
    const float* __restrict__ g, const float* __restrict__ b,
    float* __restrict__ out, const float* __restrict__ pos,
    float* __restrict__ qout)
{
    const int wave = threadIdx.x >> 6;
    const int lane = threadIdx.x & 63;
    const int tok = blockIdx.x * 4 + wave;
    const size_t base = (size_t)tok * C_ + lane * 4;

    float4 v = *(const float4*)(x + base);
    for (int p = 0; p < nparts; ++p) {
        float4 rv = *(const float4*)(r + base + (long long)p * rstride);
        v.x += rv.x; v.y += rv.y; v.z += rv.z; v.w += rv.w;
    }
    float s  = v.x + v.y + v.z + v.w;
    float ss = v.x * v.x + v.y * v.y + v.z * v.z + v.w * v.w;
    #pragma unroll
    for (int m = 32; m; m >>= 1) {
        s  += __shfl_xor(s, m);
        ss += __shfl_xor(ss, m);
    }
    float mean = s * (1.f / 256.f);
    float var  = ss * (1.f / 256.f) - mean * mean;
    float rstd = rsqrtf(var + 1e-5f);

    float4 gv = *(const float4*)(g + lane * 4);
    float4 bv = *(const float4*)(b + lane * 4);
    float4 y;
    y.x = (v.x - mean) * rstd * gv.x + bv.x;
    y.y = (v.y - mean) * rstd * gv.y + bv.y;
    y.z = (v.z - mean) * rstd * gv.z + bv.z;
    y.w = (v.w - mean) * rstd * gv.w + bv.w;
    *(float4*)(out + base) = y;
    if (qout) {
        float4 pv = *(const float4*)(pos + base);
        float4 q;
        q.x = y.x + pv.x; q.y = y.y + pv.y; q.z = y.z + pv.z; q.w = y.w + pv.w;
        *(float4*)(qout + base) = q;
    }
}

// ---------------- deformable sampling: 2 tokens/wave, 4 lanes/head; value [B][NH][S][HD] bf16 ----
__global__ __launch_bounds__(256) void deform_kernel(
    const ushort_t* __restrict__ value,   // [B][NH][S][HD] bf16 (transposed)
    const float* __restrict__ d12,        // [NTOK, 384] = offsets | aw logits
    const float* __restrict__ refpts,     // [B, LQ, NL, 2]
    ushort_t* __restrict__ out)           // [NTOK, 256] bf16, laid out (tok, h, d)
{
    const int lane = threadIdx.x & 63;
    const int wave = threadIdx.x >> 6;
    const int half = lane >> 5;
    const int tok = blockIdx.x * 8 + wave * 2 + half;
    const int h  = (lane >> 2) & 7;
    const int d8 = (lane & 3) * 8;
    const int b = tok / LQ_;

    const float* awp = d12 + (size_t)tok * 384 + 256 + h * 16;
    float logit[16];
    float mx = -1e30f;
    #pragma unroll
    for (int i = 0; i < 16; ++i) { logit[i] = awp[i]; mx = fmaxf(mx, logit[i]); }
    float sum = 0.f;
    #pragma unroll
    for (int i = 0; i < 16; ++i) { logit[i] = __expf(logit[i] - mx); sum += logit[i]; }
    float inv = 1.f / sum;

    const float* offp = d12 + (size_t)tok * 384 + h * 32;
    const float* refp = refpts + (size_t)tok * (NL_ * 2);

    const int HW[4]     = {128, 64, 32, 16};
    const int starts[4] = {0, 16384, 20480, 21504};

    float accv[8];
    #pragma unroll
    for (int i = 0; i < 8; ++i) accv[i] = 0.f;

    #pragma unroll
    for (int l = 0; l < 4; ++l) {
        const int Hl = HW[l], Wl = HW[l];
        float rx = refp[l * 2 + 0], ry = refp[l * 2 + 1];
        const ushort_t* vbase = value + (((size_t)(b * 8 + h)) * S_ + starts[l]) * HD_ + d8;
        #pragma unroll
        for (int p = 0; p < 4; ++p) {
            float ox = offp[(l * 4 + p) * 2 + 0];
            float oy = offp[(l * 4 + p) * 2 + 1];
            float xl = rx * (float)Wl + ox - 0.5f;
            float yl = ry * (float)Hl + oy - 0.5f;
            float x0f = floorf(xl), y0f = floorf(yl);
            int x0 = (int)x0f, y0 = (int)y0f;
            float wx1 = xl - x0f, wy1 = yl - y0f;
            float wx0 = 1.f - wx1, wy0 = 1.f - wy1;
            float aww = logit[l * 4 + p] * inv;

            #pragma unroll
            for (int c = 0; c < 4; ++c) {
                int dx = c & 1, dy = c >> 1;
                int xi = x0 + dx, yi = y0 + dy;
                float w = (dx ? wx1 : wx0) * (dy ? wy1 : wy0);
                bool valid = (xi >= 0) & (xi < Wl) & (yi >= 0) & (yi < Hl);
                int xc = min(max(xi, 0), Wl - 1);
                int yc = min(max(yi, 0), Hl - 1);
                float wc = (valid ? w : 0.f) * aww;
                uint4 raw = *(const uint4*)(vbase + (size_t)(yc * Wl + xc) * HD_);
                accv[0] += __uint_as_float((raw.x & 0xFFFFu) << 16) * wc;
                accv[1] += __uint_as_float(raw.x & 0xFFFF0000u) * wc;
                accv[2] += __uint_as_float((raw.y & 0xFFFFu) << 16) * wc;
                accv[3] += __uint_as_float(raw.y & 0xFFFF0000u) * wc;
                accv[4] += __uint_as_float((raw.z & 0xFFFFu) << 16) * wc;
                accv[5] += __uint_as_float(raw.z & 0xFFFF0000u) * wc;
                accv[6] += __uint_as_float((raw.w & 0xFFFFu) << 16) * wc;
                accv[7] += __uint_as_float(raw.w & 0xFFFF0000u) * wc;
            }
        }
    }
    uint4 po;
    po.x = pack_bf16(accv[0], accv[1]);
    po.y = pack_bf16(accv[2], accv[3]);
    po.z = pack_bf16(accv[4], accv[5]);
    po.w = pack_bf16(accv[6], accv[7]);
    *(uint4*)(out + (size_t)tok * C_ + h * HD_ + d8) = po;
}

// ---------------- host launch ----------------
extern "C" void kernel_launch(void* const* d_in, const int* in_sizes, int n_in,
                              void* d_out, int out_size, void* d_ws, size_t ws_size,
                              hipStream_t stream) {
    const float* tgt_text = (const float*)d_in[0];
    const float* pos      = (const float*)d_in[1];
    const float* refpts   = (const float*)d_in[2];
    const float* src      = (const float*)d_in[3];
    const float* in_proj_w  = (const float*)d_in[6];
    const float* in_proj_b  = (const float*)d_in[7];
    const float* out_proj_w = (const float*)d_in[8];
    const float* out_proj_b = (const float*)d_in[9];
    const float* ln1_g = (const float*)d_in[10];
    const float* ln1_b = (const float*)d_in[11];
    const float* samp_off_w = (const float*)d_in[12];
    const float* samp_off_b = (const float*)d_in[13];
    const float* aw_w = (const float*)d_in[14];
    const float* aw_b = (const float*)d_in[15];
    const float* vp_w = (const float*)d_in[16];
    const float* vp_b = (const float*)d_in[17];
    const float* op_w = (const float*)d_in[18];
    const float* op_b = (const float*)d_in[19];
    const float* ln2_g = (const float*)d_in[20];
    const float* ln2_b = (const float*)d_in[21];
    const float* ffn1_w = (const float*)d_in[22];
    const float* ffn1_b = (const float*)d_in[23];
    const float* ffn2_w = (const float*)d_in[24];
    const float* ffn2_b = (const float*)d_in[25];
    const float* ln3_g = (const float*)d_in[26];
    const float* ln3_b = (const float*)d_in[27];

    const long long NC = (long long)NTOK_ * C_;    // 3,840,000 floats
    float* ws = (float*)d_ws;
    float* A    = ws;                               // [NTOK,C] fp32  tgt (post-LN1/LN2)
    float* Bq   = ws + NC;                          // [NTOK,C] fp32  query
    float* Creg = ws + 2 * NC;                      // 15.36M floats: qkv+valt -> ffn hidden
    float* D12  = Creg + (long long)NTOK_ * DFF_;   // [NTOK,384] fp32 offsets|aw
    float* E    = D12 + (long long)NTOK_ * 384;     // [NTOK,C]: bf16 attn/deform out; fp32 FFN2 partial0
    float* F    = E + NC;                           // [NTOK,C] fp32 proj results / FFN2 partial1
    ushort_t* wb = (ushort_t*)(F + NC);             // bf16 weight arena (1,015,808 ushorts ~ 2 MB)

    ushort_t* qkv  = (ushort_t*)Creg;                       // [NTOK,768] bf16
    ushort_t* valt = (ushort_t*)Creg + (size_t)NTOK_ * 768; // [B][NH][S][HD] bf16

    const int MB64  = (NTOK_ + 63) / 64;    // 235
    const int MB128 = (NTOK_ + 127) / 128;  // 118
    const int MBV64 = BS_ / 64;             // 680

    // 0. convert all weights to bf16 (same rounding as per-tile pack -> bit-identical)
    convw_kernel<<<496, 256, 0, stream>>>(in_proj_w, out_proj_w, vp_w, samp_off_w,
                                          aw_w, op_w, ffn1_w, ffn2_w, wb);
    // 1. QK projection on (tgt+pos) -> qkv bf16 cols 0..511
    gemm_w<1, 1, 64><<<dim3(MB64, 4, 1), 256, 0, stream>>>(tgt_text, pos, wb + WOFF_IP,
        in_proj_b, nullptr, 0, qkv, 0, NTOK_, 512, 256, 256, 768, 0);
    // 2. V projection (tgt) -> qkv bf16 cols 512..767
    gemm_w<0, 1, 64><<<dim3(MB64, 2, 1), 256, 0, stream>>>(tgt_text, nullptr, wb + WOFF_IP + 512 * 256,
        in_proj_b + 512, nullptr, 0, qkv + 512, 0, NTOK_, 256, 256, 256, 768, 0);
    // 3. value projection (src) -> valt bf16 transposed [B][NH][S][HD]
    gemm_w<0, 2, 64><<<dim3(MBV64, 2, 1), 256, 0, stream>>>(src, nullptr, wb + WOFF_VP,
        vp_b, nullptr, 0, valt, 0, BS_, 256, 256, 256, 0, 0);
    // 4. self-attention (bf16 -> bf16)
    attn_kernel<<<B_ * Q_ * NH_, 64, 0, stream>>>(qkv, (ushort_t*)E);
    // 5. out projection (A bf16) -> F fp32
    gemm_w<2, 0, 64><<<dim3(MB64, 2, 1), 256, 0, stream>>>(E, nullptr, wb + WOFF_OUT,
        out_proj_b, nullptr, 0, F, 0, NTOK_, 256, 256, 256, 256, 0);
    // 6. LN1 (+ residual), and query = tgt + pos
    ln4_kernel<<<NTOK_ / 4, 256, 0, stream>>>(tgt_text, F, 1, 0,
                                              ln1_g, ln1_b, A, pos, Bq);
    // 7. sampling offsets + aw logits (contiguous bf16 weights, dual bias) -> fp32 D12
    gemm_w<0, 0, 64><<<dim3(MB64, 3, 1), 256, 0, stream>>>(Bq, nullptr, wb + WOFF_SO,
        samp_off_b, aw_b, 256, D12, 0, NTOK_, 384, 256, 256, 384, 0);
    // 8. deformable sampling (transposed bf16 value, bf16 out); 2 tokens per wave
    deform_kernel<<<NTOK_ / 8, 256, 0, stream>>>(valt, D12, refpts, (ushort_t*)E);
    // 9. output projection of cross-attn (A bf16) -> F fp32
    gemm_w<2, 0, 64><<<dim3(MB64, 2, 1), 256, 0, stream>>>(E, nullptr, wb + WOFF_OP,
        op_b, nullptr, 0, F, 0, NTOK_, 256, 256, 256, 256, 0);
    // 10. LN2 (+ residual), in place on A
    ln4_kernel<<<NTOK_ / 4, 256, 0, stream>>>(A, F, 1, 0,
                                              ln2_g, ln2_b, A, nullptr, nullptr);
    // 11. FFN1 + ReLU -> bf16 hidden [NTOK,1024]; 128-tile (944 blocks)
    gemm_w<0, 1, 128><<<dim3(MB128, 8, 1), 256, 0, stream>>>(A, nullptr, wb + WOFF_F1,
        ffn1_b, nullptr, 0, Creg, 0, NTOK_, DFF_, 256, 256, DFF_, 1);
    // 12. FFN2 (A bf16), 64-tile + split-K x2: partial0=E, partial1=F (=E+NC)
    gemm_w<2, 0, 64><<<dim3(MB64, 2, 2), 256, 0, stream>>>(Creg, nullptr, wb + WOFF_F2,
        ffn2_b, nullptr, 0, E, NC, NTOK_, 256, 1024, 512, 256, 0);
    // 13. LN3 (+ residual over 2 partials) -> d_out
    ln4_kernel<<<NTOK_ / 4, 256, 0, stream>>>(A, E, 2, NC,
                                              ln3_g, ln3_b, (float*)d_out, nullptr, nullptr);
}